// Round 1
// baseline (1111.013 us; speedup 1.0000x reference)
//
#include <hip/hip_runtime.h>
#include <hip/hip_bf16.h>
#include <float.h>

#define NLVL  4
#define KCB   256
#define DIMD  128
#define NROWS 262144
#define MTILE 64             // rows per workgroup (was 128): LDS ~39.9KB -> 4 blocks/CU
#define RES_STRIDE 132       // fp32 LDS row stride (pad 4, keeps 16B alignment)
#define MARGIN 0.5f
#define WLCAP 1024

typedef _Float16 half8  __attribute__((ext_vector_type(8)));
typedef float    floatx4 __attribute__((ext_vector_type(4)));

// ---------------------------------------------------------------------------
// Prep: per-entry ||c||^2 (exact fp32, same arithmetic as R1) + fp16 codebook.
// ---------------------------------------------------------------------------
__global__ __launch_bounds__(256) void rq_prep_kernel(const float* __restrict__ cb,
                                                      float* __restrict__ c2,
                                                      _Float16* __restrict__ cbh) {
    int e = blockIdx.x * 256 + threadIdx.x;   // 0..1023
    const float4* p = (const float4*)(cb + (size_t)e * DIMD);
    _Float16* ho = cbh + (size_t)e * DIMD;
    float s = 0.f;
#pragma unroll
    for (int k = 0; k < DIMD / 4; ++k) {
        float4 v = p[k];
        s = fmaf(v.x, v.x, s);
        s = fmaf(v.y, v.y, s);
        s = fmaf(v.z, v.z, s);
        s = fmaf(v.w, v.w, s);
        ho[4 * k + 0] = (_Float16)v.x;
        ho[4 * k + 1] = (_Float16)v.y;
        ho[4 * k + 2] = (_Float16)v.z;
        ho[4 * k + 3] = (_Float16)v.w;
    }
    c2[e] = s;
}

// ---------------------------------------------------------------------------
// Main fused kernel: 64 rows/block (4 blocks/CU), residual fp32 in LDS.
// Per level: fp16 MFMA GEMM -> argmin + margin filter -> exact fp32
// refinement of near-ties -> residual update. 3 barriers/level (init work
// folded into prior update phase via double-buffered refine_key).
// ---------------------------------------------------------------------------
__global__ __launch_bounds__(256, 4) void rq_main_kernel(const float* __restrict__ x,
                                                         const float* __restrict__ cb,
                                                         const float* __restrict__ c2g,
                                                         const _Float16* __restrict__ cbh,
                                                         float* __restrict__ out) {
    __shared__ float res[MTILE * RES_STRIDE];              // 33.8 KB
    __shared__ unsigned long long refine_key[2][MTILE];    // 1 KB (double-buffered)
    __shared__ int codes_lds[MTILE * 4];                   // 1 KB
    __shared__ unsigned int wl[WLCAP];                     // 4 KB
    __shared__ int wl_cnt;

    const int tid  = threadIdx.x;
    const int wave = tid >> 6;
    const int lane = tid & 63;
    const int q    = lane >> 4;     // quad 0..3
    const int c    = lane & 15;     // column / A-row selector
    const int row0 = blockIdx.x * MTILE;

    // ---- stage x tile -> LDS residual (coalesced float4) + level-0 init ----
    for (int i = tid; i < MTILE * DIMD / 4; i += 256) {
        int r_ = i >> 5, c4 = i & 31;
        float4 v = ((const float4*)x)[(size_t)(row0 + r_) * 32 + c4];
        *(float4*)&res[r_ * RES_STRIDE + c4 * 4] = v;
    }
    if (tid == 0) wl_cnt = 0;
    if (tid < MTILE) refine_key[0][tid] = ~0ULL;
    __syncthreads();

    for (int l = 0; l < NLVL; ++l) {
        const int p = l & 1;

        // per-lane c2 for my 16 candidate entries (e = t*16 + c)
        float c2v[16];
#pragma unroll
        for (int t = 0; t < 16; ++t) c2v[t] = c2g[l * KCB + t * 16 + c];

        const _Float16* cbl = cbh + (size_t)l * KCB * DIMD;

        // ---- GEMM: this wave computes rows [wave*16, wave*16+16) x 256 entries ----
        floatx4 acc[16];
#pragma unroll
        for (int t = 0; t < 16; ++t)
            acc[t] = (floatx4){0.f, 0.f, 0.f, 0.f};

#pragma unroll
        for (int s = 0; s < 4; ++s) {        // k-steps of 32
            half8 a0;
            {
                const float* pr = &res[(wave * 16 + c) * RES_STRIDE + s * 32 + q * 8];
                float4 u = *(const float4*)pr;
                float4 v = *(const float4*)(pr + 4);
                a0[0] = (_Float16)u.x; a0[1] = (_Float16)u.y;
                a0[2] = (_Float16)u.z; a0[3] = (_Float16)u.w;
                a0[4] = (_Float16)v.x; a0[5] = (_Float16)v.y;
                a0[6] = (_Float16)v.z; a0[7] = (_Float16)v.w;
            }
#pragma unroll
            for (int t = 0; t < 16; ++t) {
                half8 b = *(const half8*)(cbl + (size_t)(t * 16 + c) * DIMD + s * 32 + q * 8);
                acc[t] = __builtin_amdgcn_mfma_f32_16x16x32_f16(a0, b, acc[t], 0, 0, 0);
            }
        }

        // ---- selection: argmin + margin filter, per acc-reg (row) ----
#pragma unroll
        for (int r = 0; r < 4; ++r) {
            float bv = FLT_MAX; int be = 0;
#pragma unroll
            for (int t = 0; t < 16; ++t) {
                float d = c2v[t] - 2.f * acc[t][r];
                if (d < bv) { bv = d; be = t * 16 + c; }
            }
            // cross-lane argmin over the 16 columns (first-occurrence tiebreak)
#pragma unroll
            for (int m = 1; m < 16; m <<= 1) {
                float ov = __shfl_xor(bv, m);
                int   oe = __shfl_xor(be, m);
                if (ov < bv || (ov == bv && oe < be)) { bv = ov; be = oe; }
            }
            float thr = bv + MARGIN;
            int cnt = 0;
#pragma unroll
            for (int t = 0; t < 16; ++t)
                cnt += (c2v[t] - 2.f * acc[t][r]) <= thr;
#pragma unroll
            for (int m = 1; m < 16; m <<= 1) cnt += __shfl_xor(cnt, m);

            int row_l = wave * 16 + q * 4 + r;
            if (c == 0) codes_lds[row_l * 4 + l] = be;
            if (cnt >= 2) {
#pragma unroll
                for (int t = 0; t < 16; ++t) {
                    float d = c2v[t] - 2.f * acc[t][r];
                    if (d <= thr) {
                        int slot = atomicAdd(&wl_cnt, 1);
                        if (slot < WLCAP) wl[slot] = ((unsigned)row_l << 8) | (unsigned)(t * 16 + c);
                    }
                }
            }
        }
        __syncthreads();

        // ---- exact fp32 refinement of near-ties (bit-identical to R1's math) ----
        int n = wl_cnt; if (n > WLCAP) n = WLCAP;
        for (int i = tid; i < n; i += 256) {
            unsigned int it = wl[i];
            int row_l = it >> 8, e = it & 255;
            const float* rr = &res[row_l * RES_STRIDE];
            const float* cc = cb + ((size_t)l * KCB + e) * DIMD;
            float d = 0.f;
#pragma unroll
            for (int k = 0; k < DIMD / 4; ++k) {
                float4 rv = *(const float4*)(rr + 4 * k);
                float4 cv = *(const float4*)(cc + 4 * k);
                d = fmaf(rv.x, cv.x, d);
                d = fmaf(rv.y, cv.y, d);
                d = fmaf(rv.z, cv.z, d);
                d = fmaf(rv.w, cv.w, d);
            }
            float dist = c2g[l * KCB + e] - 2.f * d;
            unsigned int ob = __float_as_uint(dist);
            ob = (ob & 0x80000000u) ? ~ob : (ob | 0x80000000u);
            unsigned long long key = ((unsigned long long)ob << 32) | (unsigned int)e;
            atomicMin(&refine_key[p][row_l], key);
        }
        __syncthreads();

        // ---- residual update: 4 threads/row, 32 floats each; fold in next-level init ----
        {
            int row_l = tid >> 2, sub = tid & 3;
            int idx;
            unsigned long long k = refine_key[p][row_l];
            if (k != ~0ULL) idx = (int)(k & 0xFFFFFFFFULL);
            else            idx = codes_lds[row_l * 4 + l];
            if (sub == 0) codes_lds[row_l * 4 + l] = idx;
            const float4* cbr = (const float4*)(cb + ((size_t)l * KCB + idx) * DIMD + sub * 32);
            float* rr = &res[row_l * RES_STRIDE + sub * 32];
#pragma unroll
            for (int j = 0; j < 8; ++j) {
                float4 v = cbr[j];
                float4 u = *(float4*)(rr + 4 * j);
                u.x -= v.x; u.y -= v.y; u.z -= v.z; u.w -= v.w;
                *(float4*)(rr + 4 * j) = u;
            }
        }
        // reset state for next level (wl/wl_cnt reads all happened before the
        // refinement barrier; refine_key[p^1] is untouched this level)
        if (tid == 0) wl_cnt = 0;
        if (tid < MTILE) refine_key[p ^ 1][tid] = ~0ULL;
        __syncthreads();
    }

    // ---- output: recon = x - residual (coalesced), codes as float4/row ----
    for (int i = tid; i < MTILE * DIMD / 4; i += 256) {
        int r_ = i >> 5, c4 = i & 31;
        float4 xv = ((const float4*)x)[(size_t)(row0 + r_) * 32 + c4];
        float4 rv = *(const float4*)&res[r_ * RES_STRIDE + c4 * 4];
        float4 o;
        o.x = xv.x - rv.x; o.y = xv.y - rv.y;
        o.z = xv.z - rv.z; o.w = xv.w - rv.w;
        ((float4*)out)[(size_t)(row0 + r_) * 32 + c4] = o;
    }
    if (tid < MTILE) {
        const int* cl = &codes_lds[tid * 4];
        float4 cd;
        cd.x = (float)cl[0]; cd.y = (float)cl[1];
        cd.z = (float)cl[2]; cd.w = (float)cl[3];
        ((float4*)(out + (size_t)NROWS * DIMD))[row0 + tid] = cd;
    }
}

extern "C" void kernel_launch(void* const* d_in, const int* in_sizes, int n_in,
                              void* d_out, int out_size, void* d_ws, size_t ws_size,
                              hipStream_t stream) {
    const float* x  = (const float*)d_in[0];
    const float* cb = (const float*)d_in[1];
    float* out = (float*)d_out;

    float*    c2  = (float*)d_ws;                        // 4096 floats = 16 KB
    _Float16* cbh = (_Float16*)((char*)d_ws + 16384);    // 256 KB fp16 codebook

    rq_prep_kernel<<<NLVL * KCB / 256, 256, 0, stream>>>(cb, c2, cbh);
    rq_main_kernel<<<NROWS / MTILE, 256, 0, stream>>>(x, cb, c2, cbh, out);
}

// Round 2
// 936.534 us; speedup vs baseline: 1.1863x; 1.1863x over previous
//
#include <hip/hip_runtime.h>
#include <hip/hip_bf16.h>
#include <float.h>

#define NLVL  4
#define KCB   256
#define DIMD  128
#define NROWS 262144
#define WAVES 4              // waves per block; each wave fully autonomous
#define WROWS 16             // rows per wave
#define RES_STRIDE 132       // fp32 LDS row stride (pad 4, keeps 16B alignment)
#define MARGIN 0.5f
#define WLCAP_W 320          // per-wave worklist capacity (16 rows * 20 avg)

typedef _Float16 half8  __attribute__((ext_vector_type(8)));
typedef float    floatx4 __attribute__((ext_vector_type(4)));

// Wave-internal "barrier": LDS ops from one wave complete in order; this just
// forces completion of outstanding DS ops + stops the compiler reordering
// memory ops across the phase boundary. No s_barrier anywhere in the kernel.
#define WSYNC() asm volatile("s_waitcnt lgkmcnt(0)" ::: "memory")

// ---------------------------------------------------------------------------
// Prep: per-entry ||c||^2 (exact fp32, same arithmetic as reference) + fp16
// codebook copy. 1024 entries, thread-per-entry.
// ---------------------------------------------------------------------------
__global__ __launch_bounds__(256) void rq_prep_kernel(const float* __restrict__ cb,
                                                      float* __restrict__ c2,
                                                      _Float16* __restrict__ cbh) {
    int e = blockIdx.x * 256 + threadIdx.x;   // 0..1023
    const float4* p = (const float4*)(cb + (size_t)e * DIMD);
    _Float16* ho = cbh + (size_t)e * DIMD;
    float s = 0.f;
#pragma unroll
    for (int k = 0; k < DIMD / 4; ++k) {
        float4 v = p[k];
        s = fmaf(v.x, v.x, s);
        s = fmaf(v.y, v.y, s);
        s = fmaf(v.z, v.z, s);
        s = fmaf(v.w, v.w, s);
        ho[4 * k + 0] = (_Float16)v.x;
        ho[4 * k + 1] = (_Float16)v.y;
        ho[4 * k + 2] = (_Float16)v.z;
        ho[4 * k + 3] = (_Float16)v.w;
    }
    c2[e] = s;
}

// ---------------------------------------------------------------------------
// Main fused kernel, wave-autonomous: each wave owns 16 rows + a private LDS
// residual strip. Zero __syncthreads. Per level: fp16 MFMA GEMM (16x256) ->
// argmin + margin filter -> exact fp32 refinement of near-ties (same serial
// fmaf order as before) -> residual update.
// ---------------------------------------------------------------------------
__global__ __launch_bounds__(256) void rq_main_kernel(const float* __restrict__ x,
                                                      const float* __restrict__ cb,
                                                      const float* __restrict__ c2g,
                                                      const _Float16* __restrict__ cbh,
                                                      float* __restrict__ out) {
    __shared__ float res[WAVES][WROWS * RES_STRIDE];            // 33.0 KB
    __shared__ unsigned int wl[WAVES][WLCAP_W];                 // 5.0 KB
    __shared__ unsigned long long refine_key[WAVES][WROWS];     // 0.5 KB
    __shared__ int codes_lds[WAVES][WROWS][4];                  // 1.0 KB
    __shared__ int wl_cnt[WAVES];

    const int tid  = threadIdx.x;
    const int wave = tid >> 6;
    const int lane = tid & 63;
    const int q    = lane >> 4;     // quad 0..3
    const int c    = lane & 15;     // column / A-row selector
    const int rowW = blockIdx.x * (WAVES * WROWS) + wave * WROWS;  // first row of this wave

    float* resw = res[wave];

    // ---- stage this wave's 16 rows -> LDS residual (coalesced float4) ----
    for (int i = lane; i < WROWS * 32; i += 64) {
        int r_ = i >> 5, c4 = i & 31;
        float4 v = ((const float4*)x)[(size_t)(rowW + r_) * 32 + c4];
        *(float4*)&resw[r_ * RES_STRIDE + c4 * 4] = v;
    }
    if (lane == 0) wl_cnt[wave] = 0;
    if (lane < WROWS) refine_key[wave][lane] = ~0ULL;
    WSYNC();

    for (int l = 0; l < NLVL; ++l) {
        // per-lane c2 for my 16 candidate entries (e = t*16 + c), L2-hot
        float c2v[16];
#pragma unroll
        for (int t = 0; t < 16; ++t) c2v[t] = c2g[l * KCB + t * 16 + c];

        const _Float16* cbl = cbh + (size_t)l * KCB * DIMD;

        // ---- GEMM: 16 rows x 256 entries, K=128 (4 k-steps of 32) ----
        floatx4 acc[16];
#pragma unroll
        for (int t = 0; t < 16; ++t)
            acc[t] = (floatx4){0.f, 0.f, 0.f, 0.f};

#pragma unroll
        for (int s = 0; s < 4; ++s) {
            half8 a0;
            {
                const float* pr = &resw[c * RES_STRIDE + s * 32 + q * 8];
                float4 u = *(const float4*)pr;
                float4 v = *(const float4*)(pr + 4);
                a0[0] = (_Float16)u.x; a0[1] = (_Float16)u.y;
                a0[2] = (_Float16)u.z; a0[3] = (_Float16)u.w;
                a0[4] = (_Float16)v.x; a0[5] = (_Float16)v.y;
                a0[6] = (_Float16)v.z; a0[7] = (_Float16)v.w;
            }
#pragma unroll
            for (int t = 0; t < 16; ++t) {
                half8 b = *(const half8*)(cbl + (size_t)(t * 16 + c) * DIMD + s * 32 + q * 8);
                acc[t] = __builtin_amdgcn_mfma_f32_16x16x32_f16(a0, b, acc[t], 0, 0, 0);
            }
        }

        // ---- selection: argmin + margin filter, per acc-reg (row) ----
#pragma unroll
        for (int r = 0; r < 4; ++r) {
            float bv = FLT_MAX; int be = 0;
#pragma unroll
            for (int t = 0; t < 16; ++t) {
                float d = c2v[t] - 2.f * acc[t][r];
                if (d < bv) { bv = d; be = t * 16 + c; }
            }
            // cross-lane argmin over the 16 columns (stays within 16-lane group)
#pragma unroll
            for (int m = 1; m < 16; m <<= 1) {
                float ov = __shfl_xor(bv, m);
                int   oe = __shfl_xor(be, m);
                if (ov < bv || (ov == bv && oe < be)) { bv = ov; be = oe; }
            }
            float thr = bv + MARGIN;
            int cnt = 0;
#pragma unroll
            for (int t = 0; t < 16; ++t)
                cnt += (c2v[t] - 2.f * acc[t][r]) <= thr;
#pragma unroll
            for (int m = 1; m < 16; m <<= 1) cnt += __shfl_xor(cnt, m);

            int row_m = q * 4 + r;    // 0..15 within this wave
            if (c == 0) codes_lds[wave][row_m][l] = be;
            if (cnt >= 2) {
#pragma unroll
                for (int t = 0; t < 16; ++t) {
                    float d = c2v[t] - 2.f * acc[t][r];
                    if (d <= thr) {
                        int slot = atomicAdd(&wl_cnt[wave], 1);
                        if (slot < WLCAP_W)
                            wl[wave][slot] = ((unsigned)row_m << 8) | (unsigned)(t * 16 + c);
                    }
                }
            }
        }
        WSYNC();

        // ---- exact fp32 refinement of near-ties (same serial fmaf order) ----
        int n = wl_cnt[wave]; if (n > WLCAP_W) n = WLCAP_W;
        for (int i = lane; i < n; i += 64) {
            unsigned int it = wl[wave][i];
            int row_m = it >> 8, e = it & 255;
            const float* rr = &resw[row_m * RES_STRIDE];
            const float* cc = cb + ((size_t)l * KCB + e) * DIMD;
            float d = 0.f;
#pragma unroll
            for (int k = 0; k < DIMD / 4; ++k) {
                float4 rv = *(const float4*)(rr + 4 * k);
                float4 cv = *(const float4*)(cc + 4 * k);
                d = fmaf(rv.x, cv.x, d);
                d = fmaf(rv.y, cv.y, d);
                d = fmaf(rv.z, cv.z, d);
                d = fmaf(rv.w, cv.w, d);
            }
            float dist = c2g[l * KCB + e] - 2.f * d;
            unsigned int ob = __float_as_uint(dist);
            ob = (ob & 0x80000000u) ? ~ob : (ob | 0x80000000u);
            unsigned long long key = ((unsigned long long)ob << 32) | (unsigned int)e;
            atomicMin(&refine_key[wave][row_m], key);
        }
        WSYNC();

        // ---- residual update: 4 lanes/row, 32 floats each ----
        {
            int row_m = lane >> 2, sub = lane & 3;
            unsigned long long k = refine_key[wave][row_m];
            int idx;
            if (k != ~0ULL) idx = (int)(k & 0xFFFFFFFFULL);
            else            idx = codes_lds[wave][row_m][l];
            if (sub == 0) codes_lds[wave][row_m][l] = idx;
            const float4* cbr = (const float4*)(cb + ((size_t)l * KCB + idx) * DIMD + sub * 32);
            float* rr = &resw[row_m * RES_STRIDE + sub * 32];
#pragma unroll
            for (int j = 0; j < 8; ++j) {
                int je = (j + 2 * sub) & 7;   // stagger subs -> 2-way (free) LDS banks
                float4 v = cbr[je];
                float4 u = ((float4*)rr)[je];
                u.x -= v.x; u.y -= v.y; u.z -= v.z; u.w -= v.w;
                ((float4*)rr)[je] = u;
            }
        }
        // reset per-level state (all reads above issued before these writes;
        // wave LDS ops complete in order)
        if (lane == 0) wl_cnt[wave] = 0;
        if (lane < WROWS) refine_key[wave][lane] = ~0ULL;
        WSYNC();
    }

    // ---- output: recon = x - residual (coalesced), codes as float4/row ----
    for (int i = lane; i < WROWS * 32; i += 64) {
        int r_ = i >> 5, c4 = i & 31;
        float4 xv = ((const float4*)x)[(size_t)(rowW + r_) * 32 + c4];
        float4 rv = *(const float4*)&resw[r_ * RES_STRIDE + c4 * 4];
        float4 o;
        o.x = xv.x - rv.x; o.y = xv.y - rv.y;
        o.z = xv.z - rv.z; o.w = xv.w - rv.w;
        ((float4*)out)[(size_t)(rowW + r_) * 32 + c4] = o;
    }
    if (lane < WROWS) {
        const int* cl = codes_lds[wave][lane];
        float4 cd;
        cd.x = (float)cl[0]; cd.y = (float)cl[1];
        cd.z = (float)cl[2]; cd.w = (float)cl[3];
        ((float4*)(out + (size_t)NROWS * DIMD))[rowW + lane] = cd;
    }
}

extern "C" void kernel_launch(void* const* d_in, const int* in_sizes, int n_in,
                              void* d_out, int out_size, void* d_ws, size_t ws_size,
                              hipStream_t stream) {
    const float* x  = (const float*)d_in[0];
    const float* cb = (const float*)d_in[1];
    float* out = (float*)d_out;

    float*    c2  = (float*)d_ws;                        // 4096 floats = 16 KB
    _Float16* cbh = (_Float16*)((char*)d_ws + 16384);    // 256 KB fp16 codebook

    rq_prep_kernel<<<NLVL * KCB / 256, 256, 0, stream>>>(cb, c2, cbh);
    rq_main_kernel<<<NROWS / (WAVES * WROWS), 256, 0, stream>>>(x, cb, c2, cbh, out);
}

// Round 3
// 750.561 us; speedup vs baseline: 1.4802x; 1.2478x over previous
//
#include <hip/hip_runtime.h>
#include <hip/hip_bf16.h>
#include <float.h>

#define NLVL  4
#define KCB   256
#define DIMD  128
#define NROWS 262144
#define WAVES 4              // waves per block; GEMM/refine/update are wave-private
#define WROWS 16             // rows per wave -> 64 rows per block
#define RES_STRIDE 132       // fp32 LDS row stride (pad 4, keeps 16B alignment)
#define MARGIN 0.5f
#define WLCAP_W 320          // per-wave worklist capacity
#define CHUNKE 64            // codebook entries per staged chunk
#define CHUNKB (CHUNKE * DIMD * 2)   // 16 KB fp16

typedef _Float16 half8  __attribute__((ext_vector_type(8)));
typedef float    floatx4 __attribute__((ext_vector_type(4)));

// Wave-internal phase fence: wave LDS ops complete in order; forces completion
// + stops compiler reordering. Block-wide sync only around codebook staging.
#define WSYNC() asm volatile("s_waitcnt lgkmcnt(0)" ::: "memory")

// async global->LDS, 16B per lane (dest = wave-uniform base + lane*16)
__device__ __forceinline__ void glds16(const void* g, void* l) {
    __builtin_amdgcn_global_load_lds(
        (const __attribute__((address_space(1))) unsigned int*)g,
        (__attribute__((address_space(3))) unsigned int*)l, 16, 0, 0);
}

// ---------------------------------------------------------------------------
// Prep: per-entry ||c||^2 (exact fp32, same fmaf order as before) + fp16
// codebook, PRE-SWIZZLED: 16B granule j of entry e stored at j ^ (e&7).
// Staging copies linearly; the GEMM read applies the same XOR -> balanced
// LDS banks for ds_read_b128 (rule: swizzle source + read, linear LDS dest).
// ---------------------------------------------------------------------------
__global__ __launch_bounds__(256) void rq_prep_kernel(const float* __restrict__ cb,
                                                      float* __restrict__ c2,
                                                      _Float16* __restrict__ cbh) {
    int e = blockIdx.x * 256 + threadIdx.x;   // 0..1023
    const float4* p = (const float4*)(cb + (size_t)e * DIMD);
    float s = 0.f;
#pragma unroll
    for (int j = 0; j < 16; ++j) {            // granule j = floats 8j..8j+7
        float4 u = p[2 * j];
        float4 v = p[2 * j + 1];
        s = fmaf(u.x, u.x, s); s = fmaf(u.y, u.y, s);
        s = fmaf(u.z, u.z, s); s = fmaf(u.w, u.w, s);
        s = fmaf(v.x, v.x, s); s = fmaf(v.y, v.y, s);
        s = fmaf(v.z, v.z, s); s = fmaf(v.w, v.w, s);
        half8 g;
        g[0] = (_Float16)u.x; g[1] = (_Float16)u.y;
        g[2] = (_Float16)u.z; g[3] = (_Float16)u.w;
        g[4] = (_Float16)v.x; g[5] = (_Float16)v.y;
        g[6] = (_Float16)v.z; g[7] = (_Float16)v.w;
        int jd = j ^ (e & 7);
        *(half8*)(cbh + (size_t)e * DIMD + jd * 8) = g;
    }
    c2[e] = s;
}

// ---------------------------------------------------------------------------
// Main fused kernel: 64 rows/block (4 waves x 16 rows). Codebook staged in
// LDS (16KB chunks, double-buffered, global_load_lds), shared by all waves.
// Per level: 4x { prefetch next chunk || MFMA chunk } -> wave-private
// argmin+margin -> exact fp32 refinement -> residual update. Next level's
// chunk 0 prefetch overlaps selection/refine/update.
// ---------------------------------------------------------------------------
__global__ __launch_bounds__(256) void rq_main_kernel(const float* __restrict__ x,
                                                      const float* __restrict__ cb,
                                                      const float* __restrict__ c2g,
                                                      const _Float16* __restrict__ cbh,
                                                      float* __restrict__ out) {
    __shared__ float res[WAVES][WROWS * RES_STRIDE];            // 33.8 KB
    __shared__ __align__(16) char cbuf[2][CHUNKB];              // 32 KB
    __shared__ unsigned int wl[WAVES][WLCAP_W];                 // 5 KB
    __shared__ unsigned long long refine_key[WAVES][WROWS];     // 0.5 KB
    __shared__ int codes_lds[WAVES][WROWS][4];                  // 1 KB
    __shared__ int wl_cnt[WAVES];

    const int tid  = threadIdx.x;
    const int wave = tid >> 6;
    const int lane = tid & 63;
    const int q    = lane >> 4;     // quad 0..3
    const int c    = lane & 15;     // column / A-row selector
    const int rowW = blockIdx.x * (WAVES * WROWS) + wave * WROWS;

    float* resw = res[wave];
    const char* cbh_b = (const char*)cbh;

    // ---- prologue: stage x rows -> LDS residual; stage level-0 chunk 0 ----
#pragma unroll
    for (int i = 0; i < 4; ++i)   // 4 x 256 threads x 16B = 16 KB
        glds16(cbh_b + (size_t)(i * 256 + tid) * 16, &cbuf[0][(i * 256 + tid) * 16]);

    for (int i = lane; i < WROWS * 32; i += 64) {
        int r_ = i >> 5, c4 = i & 31;
        float4 v = ((const float4*)x)[(size_t)(rowW + r_) * 32 + c4];
        *(float4*)&resw[r_ * RES_STRIDE + c4 * 4] = v;
    }
    if (lane == 0) wl_cnt[wave] = 0;
    if (lane < WROWS) refine_key[wave][lane] = ~0ULL;
    __syncthreads();   // drains vmcnt: chunk 0 landed

    for (int l = 0; l < NLVL; ++l) {
        // per-lane c2 for my 16 candidate entries (e = t*16 + c), L2-hot
        float c2v[16];
#pragma unroll
        for (int t = 0; t < 16; ++t) c2v[t] = c2g[l * KCB + t * 16 + c];

        // ---- A fragments: built once per level from this wave's residual ----
        half8 a[4];
#pragma unroll
        for (int s = 0; s < 4; ++s) {
            const float* pr = &resw[c * RES_STRIDE + s * 32 + q * 8];
            float4 u = *(const float4*)pr;
            float4 v = *(const float4*)(pr + 4);
            a[s][0] = (_Float16)u.x; a[s][1] = (_Float16)u.y;
            a[s][2] = (_Float16)u.z; a[s][3] = (_Float16)u.w;
            a[s][4] = (_Float16)v.x; a[s][5] = (_Float16)v.y;
            a[s][6] = (_Float16)v.z; a[s][7] = (_Float16)v.w;
        }

        floatx4 acc[16];
#pragma unroll
        for (int t = 0; t < 16; ++t)
            acc[t] = (floatx4){0.f, 0.f, 0.f, 0.f};

        // ---- chunked GEMM: prefetch chunk c_+1 (or next level's chunk 0)
        //      while MFMA-ing chunk c_ from LDS ----
#pragma unroll
        for (int c_ = 0; c_ < 4; ++c_) {
            if (c_ < 3) {
#pragma unroll
                for (int i = 0; i < 4; ++i)
                    glds16(cbh_b + (size_t)l * KCB * DIMD * 2 + (size_t)(c_ + 1) * CHUNKB
                                 + (size_t)(i * 256 + tid) * 16,
                           &cbuf[(c_ + 1) & 1][(i * 256 + tid) * 16]);
            } else if (l < NLVL - 1) {
#pragma unroll
                for (int i = 0; i < 4; ++i)
                    glds16(cbh_b + (size_t)(l + 1) * KCB * DIMD * 2
                                 + (size_t)(i * 256 + tid) * 16,
                           &cbuf[0][(i * 256 + tid) * 16]);
            }
            const char* bb = cbuf[c_ & 1];
#pragma unroll
            for (int tl = 0; tl < 4; ++tl) {
#pragma unroll
                for (int s = 0; s < 4; ++s) {
                    int ec = tl * 16 + c;                       // entry within chunk
                    half8 b = *(const half8*)(bb + ec * 256 + ((((s << 2) | q) ^ (c & 7)) << 4));
                    acc[c_ * 4 + tl] = __builtin_amdgcn_mfma_f32_16x16x32_f16(a[s], b, acc[c_ * 4 + tl], 0, 0, 0);
                }
            }
            if (c_ < 3) __syncthreads();   // chunk c_+1 landed; buffer rotation safe
        }
        // (next-level chunk-0 loads still in flight; they overlap the phases below)

        // ---- selection: argmin + margin filter, per acc-reg (row) ----
#pragma unroll
        for (int r = 0; r < 4; ++r) {
            float bv = FLT_MAX; int be = 0;
#pragma unroll
            for (int t = 0; t < 16; ++t) {
                float d = c2v[t] - 2.f * acc[t][r];
                if (d < bv) { bv = d; be = t * 16 + c; }
            }
#pragma unroll
            for (int m = 1; m < 16; m <<= 1) {
                float ov = __shfl_xor(bv, m);
                int   oe = __shfl_xor(be, m);
                if (ov < bv || (ov == bv && oe < be)) { bv = ov; be = oe; }
            }
            float thr = bv + MARGIN;
            int cnt = 0;
#pragma unroll
            for (int t = 0; t < 16; ++t)
                cnt += (c2v[t] - 2.f * acc[t][r]) <= thr;
#pragma unroll
            for (int m = 1; m < 16; m <<= 1) cnt += __shfl_xor(cnt, m);

            int row_m = q * 4 + r;
            if (c == 0) codes_lds[wave][row_m][l] = be;
            if (cnt >= 2) {
#pragma unroll
                for (int t = 0; t < 16; ++t) {
                    float d = c2v[t] - 2.f * acc[t][r];
                    if (d <= thr) {
                        int slot = atomicAdd(&wl_cnt[wave], 1);
                        if (slot < WLCAP_W)
                            wl[wave][slot] = ((unsigned)row_m << 8) | (unsigned)(t * 16 + c);
                    }
                }
            }
        }
        WSYNC();

        // ---- exact fp32 refinement of near-ties (same serial fmaf order) ----
        int n = wl_cnt[wave]; if (n > WLCAP_W) n = WLCAP_W;
        for (int i = lane; i < n; i += 64) {
            unsigned int it = wl[wave][i];
            int row_m = it >> 8, e = it & 255;
            const float* rr = &resw[row_m * RES_STRIDE];
            const float* cc = cb + ((size_t)l * KCB + e) * DIMD;
            float d = 0.f;
#pragma unroll
            for (int k = 0; k < DIMD / 4; ++k) {
                float4 rv = *(const float4*)(rr + 4 * k);
                float4 cv = *(const float4*)(cc + 4 * k);
                d = fmaf(rv.x, cv.x, d);
                d = fmaf(rv.y, cv.y, d);
                d = fmaf(rv.z, cv.z, d);
                d = fmaf(rv.w, cv.w, d);
            }
            float dist = c2g[l * KCB + e] - 2.f * d;
            unsigned int ob = __float_as_uint(dist);
            ob = (ob & 0x80000000u) ? ~ob : (ob | 0x80000000u);
            unsigned long long key = ((unsigned long long)ob << 32) | (unsigned int)e;
            atomicMin(&refine_key[wave][row_m], key);
        }
        WSYNC();

        // ---- residual update: 4 lanes/row, 32 floats each (fp32 exact) ----
        {
            int row_m = lane >> 2, sub = lane & 3;
            unsigned long long k = refine_key[wave][row_m];
            int idx;
            if (k != ~0ULL) idx = (int)(k & 0xFFFFFFFFULL);
            else            idx = codes_lds[wave][row_m][l];
            if (sub == 0) codes_lds[wave][row_m][l] = idx;
            const float4* cbr = (const float4*)(cb + ((size_t)l * KCB + idx) * DIMD + sub * 32);
            float* rr = &resw[row_m * RES_STRIDE + sub * 32];
#pragma unroll
            for (int j = 0; j < 8; ++j) {
                int je = (j + 2 * sub) & 7;   // stagger -> 2-way (free) LDS banks
                float4 v = cbr[je];
                float4 u = ((float4*)rr)[je];
                u.x -= v.x; u.y -= v.y; u.z -= v.z; u.w -= v.w;
                ((float4*)rr)[je] = u;
            }
        }
        if (lane == 0) wl_cnt[wave] = 0;
        if (lane < WROWS) refine_key[wave][lane] = ~0ULL;
        WSYNC();
        __syncthreads();   // level end: next-level chunk 0 drained; cbuf safe
    }

    // ---- output: recon = x - residual (coalesced), codes as float4/row ----
    for (int i = lane; i < WROWS * 32; i += 64) {
        int r_ = i >> 5, c4 = i & 31;
        float4 xv = ((const float4*)x)[(size_t)(rowW + r_) * 32 + c4];
        float4 rv = *(const float4*)&resw[r_ * RES_STRIDE + c4 * 4];
        float4 o;
        o.x = xv.x - rv.x; o.y = xv.y - rv.y;
        o.z = xv.z - rv.z; o.w = xv.w - rv.w;
        ((float4*)out)[(size_t)(rowW + r_) * 32 + c4] = o;
    }
    if (lane < WROWS) {
        const int* cl = codes_lds[wave][lane];
        float4 cd;
        cd.x = (float)cl[0]; cd.y = (float)cl[1];
        cd.z = (float)cl[2]; cd.w = (float)cl[3];
        ((float4*)(out + (size_t)NROWS * DIMD))[rowW + lane] = cd;
    }
}

extern "C" void kernel_launch(void* const* d_in, const int* in_sizes, int n_in,
                              void* d_out, int out_size, void* d_ws, size_t ws_size,
                              hipStream_t stream) {
    const float* x  = (const float*)d_in[0];
    const float* cb = (const float*)d_in[1];
    float* out = (float*)d_out;

    float*    c2  = (float*)d_ws;                        // 4096 floats = 16 KB
    _Float16* cbh = (_Float16*)((char*)d_ws + 16384);    // 256 KB fp16 codebook (swizzled)

    rq_prep_kernel<<<NLVL * KCB / 256, 256, 0, stream>>>(cb, c2, cbh);
    rq_main_kernel<<<NROWS / (WAVES * WROWS), 256, 0, stream>>>(x, cb, c2, cbh, out);
}

// Round 4
// 511.068 us; speedup vs baseline: 2.1739x; 1.4686x over previous
//
#include <hip/hip_runtime.h>
#include <float.h>

#define NLVL  4
#define KCB   256
#define DIMD  128
#define NROWS 262144
#define WROWS 16             // rows per wave; 1 wave per block, zero barriers
#define MARGIN 0.5f
#define WLCAP 256
#define RING  8              // LDS ring slots, 1KB each (16 entries x 32 k fp16)
#define ADV   6              // chunks kept in flight (steady-state vmcnt(5))

typedef _Float16 half8  __attribute__((ext_vector_type(8)));
typedef float    floatx4 __attribute__((ext_vector_type(4)));

// wave-internal phase fence (single-wave blocks: no s_barrier anywhere)
#define WSYNC() asm volatile("s_waitcnt lgkmcnt(0)" ::: "memory")
#define VMW(N)  asm volatile("s_waitcnt vmcnt(" #N ")" ::: "memory")

// async global->LDS, 16B/lane (LDS dest = wave-uniform base + lane*16)
__device__ __forceinline__ void glds16(const void* g, void* l) {
    __builtin_amdgcn_global_load_lds(
        (const __attribute__((address_space(1))) unsigned int*)g,
        (__attribute__((address_space(3))) unsigned int*)l, 16, 0, 0);
}

// ---------------------------------------------------------------------------
// Prep: per-entry ||c||^2 (exact fp32, same fmaf order as always) + linear
// fp16 codebook copy. 1024 entries, thread-per-entry.
// ---------------------------------------------------------------------------
__global__ __launch_bounds__(256) void rq_prep_kernel(const float* __restrict__ cb,
                                                      float* __restrict__ c2,
                                                      _Float16* __restrict__ cbh) {
    int e = blockIdx.x * 256 + threadIdx.x;   // 0..1023
    const float4* p = (const float4*)(cb + (size_t)e * DIMD);
    _Float16* ho = cbh + (size_t)e * DIMD;
    float s = 0.f;
#pragma unroll
    for (int k = 0; k < DIMD / 4; ++k) {
        float4 v = p[k];
        s = fmaf(v.x, v.x, s);
        s = fmaf(v.y, v.y, s);
        s = fmaf(v.z, v.z, s);
        s = fmaf(v.w, v.w, s);
        ho[4 * k + 0] = (_Float16)v.x;
        ho[4 * k + 1] = (_Float16)v.y;
        ho[4 * k + 2] = (_Float16)v.z;
        ho[4 * k + 3] = (_Float16)v.w;
    }
    c2[e] = s;
}

// ---------------------------------------------------------------------------
// Main kernel: 1 wave / 16 rows per block. Residual lives in 32 VGPRs/lane in
// MFMA A-fragment layout (lane(q,c): row c, k = s*32+q*8+j). Codebook B
// streams through an 8KB LDS ring (1KB chunks = 16 entries x 32 k), 6 chunks
// in flight via global_load_lds + counted vmcnt. Prefetch never stops across
// level boundaries. Zero barriers, zero LDS for the residual.
// ---------------------------------------------------------------------------
__global__ __launch_bounds__(64, 3) void rq_main_kernel(const float* __restrict__ x,
                                                        const float* __restrict__ cb,
                                                        const float* __restrict__ c2g,
                                                        const _Float16* __restrict__ cbh,
                                                        float* __restrict__ out) {
    __shared__ __align__(16) char ring[RING * 1024];            // 8 KB
    __shared__ unsigned int wl[WLCAP];                          // 1 KB
    __shared__ unsigned long long refine_key[WROWS];            // 128 B
    __shared__ int codes_lds[WROWS][4];                         // 256 B
    __shared__ int wl_cnt;

    const int lane = threadIdx.x;          // 64-thread block = 1 wave
    const int q    = lane >> 4;            // 0..3
    const int c    = lane & 15;            // 0..15 (row / entry-column selector)
    const int rowW = blockIdx.x * WROWS;
    // staging role: lane -> (entry e_loc = lane>>2, k-granule kq = lane&3)
    const int lane_off = ((lane >> 2) << 8) | ((lane & 3) << 4);
    const char* cbh_b = (const char*)cbh;

    // ---- ring prologue: chunks 0..ADV-1 in flight ----
    // chunk g: level g>>6, tile t=(g&63)>>2 (16 entries), k-step s=g&3 (32 k)
#pragma unroll
    for (int g = 0; g < ADV; ++g) {
        const char* src = cbh_b + ((g >> 6) << 16) + (((g & 63) >> 2) << 12)
                        + ((g & 3) << 6) + lane_off;
        glds16(src, ring + ((g & (RING - 1)) << 10));
    }

    // ---- stage x -> residual registers ----
    float res_[32];
#pragma unroll
    for (int s = 0; s < 4; ++s) {
        const float* px = x + (size_t)(rowW + c) * DIMD + s * 32 + q * 8;
        float4 u = *(const float4*)px;
        float4 v = *(const float4*)(px + 4);
        res_[s*8+0]=u.x; res_[s*8+1]=u.y; res_[s*8+2]=u.z; res_[s*8+3]=u.w;
        res_[s*8+4]=v.x; res_[s*8+5]=v.y; res_[s*8+6]=v.z; res_[s*8+7]=v.w;
    }
    if (lane == 0) wl_cnt = 0;
    if (lane < WROWS) refine_key[lane] = ~0ULL;
    WSYNC();

    for (int l = 0; l < NLVL; ++l) {
        // ---- A fragments from residual regs (layout matches exactly) ----
        half8 a[4];
#pragma unroll
        for (int s = 0; s < 4; ++s)
#pragma unroll
            for (int j = 0; j < 8; ++j)
                a[s][j] = (_Float16)res_[s * 8 + j];

        floatx4 acc[16];
#pragma unroll
        for (int t = 0; t < 16; ++t) acc[t] = (floatx4){0.f, 0.f, 0.f, 0.f};

        // ---- streamed GEMM: 64 chunks, ring always ADV ahead ----
#pragma unroll
        for (int w = 0; w < 64; ++w) {
            if      (w <  59) VMW(5);      // steady state: 5 newer chunks in flight
            else if (w == 59) VMW(4);      // taper (also covers last level's tail)
            else if (w == 60) VMW(3);
            else if (w == 61) VMW(2);
            else if (w == 62) VMW(1);
            else              VMW(0);
            // B frag: entry c of tile w>>2, k-granule q of k-step w&3
            half8 b = *(const half8*)(ring + ((w & (RING - 1)) << 10) + (c << 6) + (q << 4));
            if (l < NLVL - 1 || w < 64 - ADV) {     // continuous cross-level prefetch
                int g2 = l * 64 + w + ADV;
                const char* src = cbh_b + ((g2 >> 6) << 16) + (((g2 & 63) >> 2) << 12)
                                + ((g2 & 3) << 6) + lane_off;
                glds16(src, ring + ((g2 & (RING - 1)) << 10));
            }
            acc[w >> 2] = __builtin_amdgcn_mfma_f32_16x16x32_f16(a[w & 3], b, acc[w >> 2], 0, 0, 0);
        }

        // per-lane c2 for my 16 candidate entries (loaded late: short live range)
        float c2v[16];
#pragma unroll
        for (int t = 0; t < 16; ++t) c2v[t] = c2g[l * KCB + t * 16 + c];

        // ---- selection: argmin + margin filter (identical logic to R0) ----
#pragma unroll
        for (int r = 0; r < 4; ++r) {
            float bv = FLT_MAX; int be = 0;
#pragma unroll
            for (int t = 0; t < 16; ++t) {
                float d = c2v[t] - 2.f * acc[t][r];
                if (d < bv) { bv = d; be = t * 16 + c; }
            }
#pragma unroll
            for (int m = 1; m < 16; m <<= 1) {
                float ov = __shfl_xor(bv, m);
                int   oe = __shfl_xor(be, m);
                if (ov < bv || (ov == bv && oe < be)) { bv = ov; be = oe; }
            }
            float thr = bv + MARGIN;
            int cnt = 0;
#pragma unroll
            for (int t = 0; t < 16; ++t)
                cnt += (c2v[t] - 2.f * acc[t][r]) <= thr;
#pragma unroll
            for (int m = 1; m < 16; m <<= 1) cnt += __shfl_xor(cnt, m);

            int row_m = q * 4 + r;
            if (c == 0) codes_lds[row_m][l] = be;
            if (cnt >= 2) {
#pragma unroll
                for (int t = 0; t < 16; ++t) {
                    float d = c2v[t] - 2.f * acc[t][r];
                    if (d <= thr) {
                        int slot = atomicAdd(&wl_cnt, 1);
                        if (slot < WLCAP)
                            wl[slot] = ((unsigned)row_m << 8) | (unsigned)(t * 16 + c);
                    }
                }
            }
        }
        WSYNC();

        // ---- exact fp32 refinement of near-ties (4 lanes per candidate) ----
        int n = wl_cnt; if (n > WLCAP) n = WLCAP;
        for (int i = 0; i < n; ++i) {
            unsigned int it = wl[i];                 // broadcast read
            int row_m = (int)(it >> 8), e = (int)(it & 255u);
            bool act = (c == row_m);
            float d = 0.f;
            if (act) {
                const float* cc = cb + ((size_t)l * KCB + e) * DIMD + q * 8;
#pragma unroll
                for (int s = 0; s < 4; ++s) {
                    float4 u = *(const float4*)(cc + s * 32);
                    float4 v = *(const float4*)(cc + s * 32 + 4);
                    d = fmaf(res_[s*8+0], u.x, d); d = fmaf(res_[s*8+1], u.y, d);
                    d = fmaf(res_[s*8+2], u.z, d); d = fmaf(res_[s*8+3], u.w, d);
                    d = fmaf(res_[s*8+4], v.x, d); d = fmaf(res_[s*8+5], v.y, d);
                    d = fmaf(res_[s*8+6], v.z, d); d = fmaf(res_[s*8+7], v.w, d);
                }
            }
            d += __shfl_xor(d, 16);                  // reduce over q (partners share c)
            d += __shfl_xor(d, 32);
            if (act && q == 0) {
                float dist = c2g[l * KCB + e] - 2.f * d;
                unsigned int ob = __float_as_uint(dist);
                ob = (ob & 0x80000000u) ? ~ob : (ob | 0x80000000u);
                unsigned long long key = ((unsigned long long)ob << 32) | (unsigned int)e;
                atomicMin(&refine_key[row_m], key);
            }
        }
        WSYNC();

        // ---- residual update in registers (exact fp32, per-element) ----
        {
            unsigned long long k = refine_key[c];
            int idx = (k != ~0ULL) ? (int)(k & 0xFFFFFFFFULL) : codes_lds[c][l];
            if (q == 0) codes_lds[c][l] = idx;
            const float* cbase = cb + ((size_t)l * KCB + idx) * DIMD + q * 8;
#pragma unroll
            for (int s = 0; s < 4; ++s) {
                float4 u = *(const float4*)(cbase + s * 32);
                float4 v = *(const float4*)(cbase + s * 32 + 4);
                res_[s*8+0] -= u.x; res_[s*8+1] -= u.y;
                res_[s*8+2] -= u.z; res_[s*8+3] -= u.w;
                res_[s*8+4] -= v.x; res_[s*8+5] -= v.y;
                res_[s*8+6] -= v.z; res_[s*8+7] -= v.w;
            }
        }
        if (lane == 0) wl_cnt = 0;
        if (lane < WROWS) refine_key[lane] = ~0ULL;
        WSYNC();
    }

    // ---- output: recon = x - residual; codes as float4/row ----
#pragma unroll
    for (int s = 0; s < 4; ++s) {
        const float* px = x + (size_t)(rowW + c) * DIMD + s * 32 + q * 8;
        float4 u = *(const float4*)px;
        float4 v = *(const float4*)(px + 4);
        float4 o0, o1;
        o0.x = u.x - res_[s*8+0]; o0.y = u.y - res_[s*8+1];
        o0.z = u.z - res_[s*8+2]; o0.w = u.w - res_[s*8+3];
        o1.x = v.x - res_[s*8+4]; o1.y = v.y - res_[s*8+5];
        o1.z = v.z - res_[s*8+6]; o1.w = v.w - res_[s*8+7];
        float* po = out + (size_t)(rowW + c) * DIMD + s * 32 + q * 8;
        *(float4*)po = o0;
        *(float4*)(po + 4) = o1;
    }
    if (lane < WROWS) {
        float4 cd;
        cd.x = (float)codes_lds[lane][0];
        cd.y = (float)codes_lds[lane][1];
        cd.z = (float)codes_lds[lane][2];
        cd.w = (float)codes_lds[lane][3];
        ((float4*)(out + (size_t)NROWS * DIMD))[rowW + lane] = cd;
    }
}

extern "C" void kernel_launch(void* const* d_in, const int* in_sizes, int n_in,
                              void* d_out, int out_size, void* d_ws, size_t ws_size,
                              hipStream_t stream) {
    const float* x  = (const float*)d_in[0];
    const float* cb = (const float*)d_in[1];
    float* out = (float*)d_out;

    float*    c2  = (float*)d_ws;                        // 4096 floats = 16 KB
    _Float16* cbh = (_Float16*)((char*)d_ws + 16384);    // 256 KB fp16 codebook (linear)

    rq_prep_kernel<<<NLVL * KCB / 256, 256, 0, stream>>>(cb, c2, cbh);
    rq_main_kernel<<<NROWS / WROWS, 64, 0, stream>>>(x, cb, c2, cbh, out);
}